// Round 1
// baseline (112.533 us; speedup 1.0000x reference)
//
#include <hip/hip_runtime.h>
#include <math.h>

#define IMH 512
#define IMW 512
#define T   32      // output tile
#define GS  40      // gray tile (T+8)
#define BS  36      // blurred tile (T+4)
#define MS  34      // magnitude tile (T+2)

__device__ __forceinline__ int reflect_i(int v, int n) {
    if (v < 0) v = -v;
    if (v >= n) v = 2 * n - 2 - v;
    return v;
}
__device__ __forceinline__ int clamp_i(int v, int n) {
    return v < 0 ? 0 : (v >= n ? n - 1 : v);
}

__global__ __launch_bounds__(256)
void canny_mag_kernel(const float* __restrict__ data, float* __restrict__ out) {
    const int bx0 = blockIdx.x * T;
    const int by0 = blockIdx.y * T;
    const int b   = blockIdx.z;
    const int tid = threadIdx.x;

    __shared__ float sG[GS][GS + 1];   // gray, raw coords [by0-4, by0+T+4), reflect-mapped
    __shared__ float sH[GS][BS + 1];   // h-blur: raw rows x clamped cols
    __shared__ float sB[BS][BS + 1];   // blurred at clamped coords [by0-2, by0+T+2)
    __shared__ float sM[MS][MS + 1];   // magnitude, 0 outside image

    // gaussian 1d, ksize=5 sigma=1, normalized
    const float w0 = 0.05448868f, w1 = 0.24420134f, w2 = 0.40261995f;

    const float* p0 = data + ((size_t)b * 3 + 0) * (IMH * IMW);
    const float* p1 = data + ((size_t)b * 3 + 1) * (IMH * IMW);
    const float* p2 = data + ((size_t)b * 3 + 2) * (IMH * IMW);

    // Phase 1: gray = 0.299R + 0.587G + 0.114B of x=(d+1)/2, reflect indexing
    for (int idx = tid; idx < GS * GS; idx += 256) {
        int i = idx / GS, j = idx % GS;
        int ry = reflect_i(by0 - 4 + i, IMH);
        int rx = reflect_i(bx0 - 4 + j, IMW);
        int off = ry * IMW + rx;
        float r = (p0[off] + 1.0f) * 0.5f;
        float g = (p1[off] + 1.0f) * 0.5f;
        float bl = (p2[off] + 1.0f) * 0.5f;
        sG[i][j] = 0.299f * r + 0.587f * g + 0.114f * bl;
    }
    __syncthreads();

    // Phase 2: horizontal gaussian. col slot j <-> clamped coord clamp(bx0-2+j)
    for (int idx = tid; idx < GS * BS; idx += 256) {
        int i = idx / BS, j = idx % BS;
        int cx = clamp_i(bx0 - 2 + j, IMW);
        int cj = cx - bx0 + 4;  // slot in sG
        sH[i][j] = w0 * sG[i][cj - 2] + w1 * sG[i][cj - 1] + w2 * sG[i][cj]
                 + w1 * sG[i][cj + 1] + w0 * sG[i][cj + 2];
    }
    __syncthreads();

    // Phase 3: vertical gaussian. row slot jy <-> clamped coord clamp(by0-2+jy)
    for (int idx = tid; idx < BS * BS; idx += 256) {
        int jy = idx / BS, jx = idx % BS;
        int cy = clamp_i(by0 - 2 + jy, IMH);
        int ci = cy - by0 + 4;  // row slot in sH
        sB[jy][jx] = w0 * sH[ci - 2][jx] + w1 * sH[ci - 1][jx] + w2 * sH[ci][jx]
                   + w1 * sH[ci + 1][jx] + w0 * sH[ci + 2][jx];
    }
    __syncthreads();

    // Phase 4: sobel magnitude tile; zero outside image (NMS zero-padding)
    for (int idx = tid; idx < MS * MS; idx += 256) {
        int iy = idx / MS, ix = idx % MS;
        int my = by0 - 1 + iy, mx = bx0 - 1 + ix;
        float m = 0.0f;
        if (my >= 0 && my < IMH && mx >= 0 && mx < IMW) {
            int jy = iy + 1, jx = ix + 1;  // slot in sB (stores edge-clamped blurred)
            float a00 = sB[jy - 1][jx - 1], a01 = sB[jy - 1][jx], a02 = sB[jy - 1][jx + 1];
            float a10 = sB[jy][jx - 1],                            a12 = sB[jy][jx + 1];
            float a20 = sB[jy + 1][jx - 1], a21 = sB[jy + 1][jx], a22 = sB[jy + 1][jx + 1];
            float gx = (a02 - a00) + 2.0f * (a12 - a10) + (a22 - a20);
            float gy = (a20 - a00) + 2.0f * (a21 - a01) + (a22 - a02);
            m = sqrtf(gx * gx + gy * gy + 1e-6f);
        }
        sM[iy][ix] = m;
    }
    __syncthreads();

    // Phase 5: angle + NMS + write. 4 pixels/thread.
    // offs[i] = (dy,dx): (0,1)(-1,1)(-1,0)(-1,-1)(0,-1)(1,-1)(1,0)(1,1)
    // nibble tables: value+1 packed 4b per index (digit ai from LSB)
    const unsigned DYP1 = 0x22210001u;  // dy+1 per ai
    const unsigned DXP1 = 0x21000122u;  // dx+1 per ai
    const int lx = tid & 31;
    const int lyb = tid >> 5;  // 0..7
    for (int r = 0; r < 4; ++r) {
        int ly = lyb + 8 * r;
        int jy = ly + 2, jx = lx + 2;
        float a00 = sB[jy - 1][jx - 1], a01 = sB[jy - 1][jx], a02 = sB[jy - 1][jx + 1];
        float a10 = sB[jy][jx - 1],                            a12 = sB[jy][jx + 1];
        float a20 = sB[jy + 1][jx - 1], a21 = sB[jy + 1][jx], a22 = sB[jy + 1][jx + 1];
        float gx = (a02 - a00) + 2.0f * (a12 - a10) + (a22 - a20);
        float gy = (a20 - a00) + 2.0f * (a21 - a01) + (a22 - a02);
        float mag = sM[ly + 1][lx + 1];

        float deg = atan2f(gy, gx) * 57.29577951308232f;  // rad2deg
        int ai = (int)rintf(deg / 45.0f);                 // round half-even = jnp.round
        ai = ((ai % 8) + 8) % 8;                          // numpy modulo
        int dy = (int)((DYP1 >> (ai * 4)) & 0xFu) - 1;
        int dx = (int)((DXP1 >> (ai * 4)) & 0xFu) - 1;

        float sp = mag - sM[ly + 1 + dy][lx + 1 + dx];
        float sn = mag - sM[ly + 1 - dy][lx + 1 - dx];
        float o = (fminf(sp, sn) > 0.0f) ? mag : 0.0f;
        out[(size_t)b * (IMH * IMW) + (size_t)(by0 + ly) * IMW + (bx0 + lx)] = o;
    }
}

extern "C" void kernel_launch(void* const* d_in, const int* in_sizes, int n_in,
                              void* d_out, int out_size, void* d_ws, size_t ws_size,
                              hipStream_t stream) {
    const float* data = (const float*)d_in[0];
    float* out = (float*)d_out;
    int B = in_sizes[0] / (3 * IMH * IMW);  // 16
    dim3 grid(IMW / T, IMH / T, B);
    canny_mag_kernel<<<grid, dim3(256, 1, 1), 0, stream>>>(data, out);
}

// Round 2
// 104.231 us; speedup vs baseline: 1.0796x; 1.0796x over previous
//
#include <hip/hip_runtime.h>
#include <math.h>

#define IMH 512
#define IMW 512
#define T   32      // output tile
#define GS  40      // gray tile (T+8)
#define BS  36      // blurred tile (T+4)
#define MS  34      // magnitude tile (T+2)

// LDS pool layout (floats). sGX/sGY alias the dead sG/sH region in phase 4+.
#define LG  44                  // sG row stride (mult of 4 -> aligned b128 writes)
#define OG  0                   // sG: 40 x 44            [0,1760)
#define LH  37
#define OH  1760                // sH: 40 x 37            [1760,3240)
#define LB  37
#define OB  3240                // sB: 36 x 37            [3240,4572)
#define LM  35
#define OM  4572                // sM: 34 x 35            [4572,5762)
#define LX  33
#define OGX 0                   // sGX: 32 x 33           [0,1056)   (aliases sG)
#define OGY 1056                // sGY: 32 x 33           [1056,2112)(aliases sG/sH)
#define NPOOL 5762              // 23048 B

__device__ __forceinline__ int reflect_i(int v, int n) {
    if (v < 0) v = -v;
    if (v >= n) v = 2 * n - 2 - v;
    return v;
}
__device__ __forceinline__ int clamp_i(int v, int n) {
    return v < 0 ? 0 : (v >= n ? n - 1 : v);
}

__global__ __launch_bounds__(256)
void canny_mag_kernel(const float* __restrict__ data, float* __restrict__ out) {
    __shared__ float sP[NPOOL];
    const int bx0 = blockIdx.x * T;
    const int by0 = blockIdx.y * T;
    const int b   = blockIdx.z;
    const int tid = threadIdx.x;
    const bool xin = (bx0 >= 4) && (bx0 + T + 4 <= IMW);                 // no x-reflect needed
    const bool bin = (bx0 >= 1) && (bx0 + T + 1 <= IMW) &&
                     (by0 >= 1) && (by0 + T + 1 <= IMH);                 // no NMS zero-border

    const float w0 = 0.05448868f, w1 = 0.24420134f, w2 = 0.40261995f;
    const size_t plane = (size_t)IMH * IMW;
    const float* p0 = data + (size_t)b * 3 * plane;
    const float* p1 = p0 + plane;
    const float* p2 = p1 + plane;

    // Phase 1: gray = 0.1495*R + 0.2935*G + 0.057*B + 0.5  (== weighted (d+1)/2)
    if (xin) {
        // vectorized: 10 float4 per row, base (bx0-4) is 16B aligned (bx0 % 32 == 0)
        for (int idx = tid; idx < GS * 10; idx += 256) {
            int r = idx / 10, c4 = idx - r * 10;
            int ry = reflect_i(by0 - 4 + r, IMH);
            int off = ry * IMW + (bx0 - 4) + c4 * 4;
            const float4 a = *(const float4*)(p0 + off);
            const float4 g = *(const float4*)(p1 + off);
            const float4 c = *(const float4*)(p2 + off);
            float4 o;
            o.x = 0.1495f * a.x + 0.2935f * g.x + 0.057f * c.x + 0.5f;
            o.y = 0.1495f * a.y + 0.2935f * g.y + 0.057f * c.y + 0.5f;
            o.z = 0.1495f * a.z + 0.2935f * g.z + 0.057f * c.z + 0.5f;
            o.w = 0.1495f * a.w + 0.2935f * g.w + 0.057f * c.w + 0.5f;
            *(float4*)&sP[OG + r * LG + c4 * 4] = o;
        }
    } else {
        for (int idx = tid; idx < GS * GS; idx += 256) {
            int i = idx / GS, j = idx - i * GS;
            int ry = reflect_i(by0 - 4 + i, IMH);
            int rx = reflect_i(bx0 - 4 + j, IMW);
            int off = ry * IMW + rx;
            sP[OG + i * LG + j] = 0.1495f * p0[off] + 0.2935f * p1[off] + 0.057f * p2[off] + 0.5f;
        }
    }
    __syncthreads();

    // Phase 2: horizontal gaussian (cols clamped = edge pad)
    for (int idx = tid; idx < GS * BS; idx += 256) {
        int i = idx / BS, j = idx - i * BS;
        int cj = xin ? (j + 2) : (clamp_i(bx0 - 2 + j, IMW) - bx0 + 4);
        const float* g = &sP[OG + i * LG + cj];
        sP[OH + i * LH + j] = w0 * (g[-2] + g[2]) + w1 * (g[-1] + g[1]) + w2 * g[0];
    }
    __syncthreads();

    // Phase 3: vertical gaussian (rows clamped)
    for (int idx = tid; idx < BS * BS; idx += 256) {
        int jy = idx / BS, jx = idx - jy * BS;
        int ci = clamp_i(by0 - 2 + jy, IMH) - by0 + 4;
        const float* h = &sP[OH + ci * LH + jx];
        sP[OB + jy * LB + jx] = w0 * (h[-2 * LH] + h[2 * LH]) + w1 * (h[-LH] + h[LH]) + w2 * h[0];
    }
    __syncthreads();

    // Phase 4: sobel -> magnitude tile (0 outside image); stash gx,gy for interior px
    for (int idx = tid; idx < MS * MS; idx += 256) {
        int iy = idx / MS, ix = idx - iy * MS;
        const float* bb = &sP[OB + (iy + 1) * LB + (ix + 1)];
        float a00 = bb[-LB - 1], a01 = bb[-LB], a02 = bb[-LB + 1];
        float a10 = bb[-1],                      a12 = bb[1];
        float a20 = bb[LB - 1],  a21 = bb[LB],  a22 = bb[LB + 1];
        float gx = (a02 - a00) + 2.0f * (a12 - a10) + (a22 - a20);
        float gy = (a20 - a00) + 2.0f * (a21 - a01) + (a22 - a02);
        float m = sqrtf(gx * gx + gy * gy + 1e-6f);
        if (!bin) {
            int my = by0 - 1 + iy, mx = bx0 - 1 + ix;
            if (my < 0 || my >= IMH || mx < 0 || mx >= IMW) m = 0.0f;
        }
        sP[OM + iy * LM + ix] = m;
        int iyy = iy - 1, ixx = ix - 1;
        if ((unsigned)iyy < 32u && (unsigned)ixx < 32u) {
            sP[OGX + iyy * LX + ixx] = gx;
            sP[OGY + iyy * LX + ixx] = gy;
        }
    }
    __syncthreads();

    // Phase 5: octant classification (no atan2) + NMS + store. 4 px/thread.
    // Axis only matters (pos/neg dirs are min'ed together):
    //   ay <= tan(22.5)*ax -> E-W ; ay >= tan(67.5)*ax -> N-S ; else diagonal by sign(gx*gy).
    // Tie handling matches round-half-even: 22.5 -> 0 (E-W), 67.5 -> 2 (N-S).
    const int lx  = tid & 31;
    const int lyb = tid >> 5;
    size_t obase = (size_t)b * plane + (size_t)(by0 + lyb) * IMW + (bx0 + lx);
    for (int r = 0; r < 4; ++r) {
        int ly = lyb + 8 * r;
        float mag = sP[OM + (ly + 1) * LM + (lx + 1)];
        float gx = sP[OGX + ly * LX + lx];
        float gy = sP[OGY + ly * LX + lx];
        float ax = fabsf(gx), ay = fabsf(gy);
        int dy, dx;
        if (ay <= 0.41421356237f * ax)      { dy = 0; dx = 1; }
        else if (ay >= 2.41421356237f * ax) { dy = 1; dx = 0; }
        else                                { dx = 1; dy = (gx * gy > 0.0f) ? -1 : 1; }
        float n1 = sP[OM + (ly + 1 + dy) * LM + (lx + 1 + dx)];
        float n2 = sP[OM + (ly + 1 - dy) * LM + (lx + 1 - dx)];
        float o = (mag > n1 && mag > n2) ? mag : 0.0f;
        out[obase + (size_t)(8 * r) * IMW] = o;
    }
}

extern "C" void kernel_launch(void* const* d_in, const int* in_sizes, int n_in,
                              void* d_out, int out_size, void* d_ws, size_t ws_size,
                              hipStream_t stream) {
    const float* data = (const float*)d_in[0];
    float* out = (float*)d_out;
    int B = in_sizes[0] / (3 * IMH * IMW);  // 16
    dim3 grid(IMW / T, IMH / T, B);
    canny_mag_kernel<<<grid, dim3(256, 1, 1), 0, stream>>>(data, out);
}